// Round 1
// baseline (256.203 us; speedup 1.0000x reference)
//
#include <hip/hip_runtime.h>

typedef unsigned short u16;
typedef __attribute__((ext_vector_type(8))) short short8;
typedef __attribute__((ext_vector_type(4))) float f32x4;

// ---------- helpers ----------
__device__ inline u16 f2bf(float f) {
    union { float f; unsigned u; } v; v.f = f;
    unsigned u = v.u;
    unsigned r = (u + 0x7FFFu + ((u >> 16) & 1u)) >> 16;
    return (u16)r;
}
__device__ inline float bf2f(u16 h) {
    union { unsigned u; float f; } v; v.u = ((unsigned)h) << 16;
    return v.f;
}
__device__ inline float ftanh(float x) {
    float e = __expf(2.f * x);
    return 1.f - 2.f / (e + 1.f);
}
__device__ inline float4 bf4f(ushort4 u) {
    float4 f; f.x = bf2f(u.x); f.y = bf2f(u.y); f.z = bf2f(u.z); f.w = bf2f(u.w);
    return f;
}

// ---------- kernel 1: mask + bf16 cast + row norms; tail blocks do W transpose ----------
__global__ __launch_bounds__(128) void prep_kernel(
    const float* __restrict__ F0r, const float* __restrict__ F1r,
    const float* __restrict__ m0, const float* __restrict__ m1,
    const float* __restrict__ W0, const float* __restrict__ W1,
    u16* __restrict__ F0b, u16* __restrict__ F1b,
    u16* __restrict__ WT0, u16* __restrict__ WT1,
    float* __restrict__ sq0, float* __restrict__ sq1)
{
    int bx = blockIdx.x;
    int t = threadIdx.x;
    if (bx >= 16384) {
        // W [S,D] fp32 -> WT [D,S] bf16  (2*131072 elements, 2048 blocks)
        int idx = (bx - 16384) * 128 + t;
        int a = idx >> 17;
        int r = idx & 131071;
        int s = r >> 9, d = r & 511;
        const float* W = a ? W1 : W0;
        u16* WT = a ? WT1 : WT0;
        WT[d * 256 + s] = f2bf(W[r]);
        return;
    }
    int bs = bx;                  // b*256 + s
    size_t base = (size_t)bs * 512 + t * 4;
    float mk0 = m0[bs], mk1 = m1[bs];
    float4 v0 = *(const float4*)(F0r + base);
    float4 v1 = *(const float4*)(F1r + base);
    v0.x *= mk0; v0.y *= mk0; v0.z *= mk0; v0.w *= mk0;
    v1.x *= mk1; v1.y *= mk1; v1.z *= mk1; v1.w *= mk1;
    ushort4 u0; u0.x = f2bf(v0.x); u0.y = f2bf(v0.y); u0.z = f2bf(v0.z); u0.w = f2bf(v0.w);
    ushort4 u1; u1.x = f2bf(v1.x); u1.y = f2bf(v1.y); u1.z = f2bf(v1.z); u1.w = f2bf(v1.w);
    *(ushort4*)(F0b + base) = u0;
    *(ushort4*)(F1b + base) = u1;
    float s0p = v0.x*v0.x + v0.y*v0.y + v0.z*v0.z + v0.w*v0.w;
    float s1p = v1.x*v1.x + v1.y*v1.y + v1.z*v1.z + v1.w*v1.w;
    #pragma unroll
    for (int off = 32; off > 0; off >>= 1) {
        s0p += __shfl_xor(s0p, off);
        s1p += __shfl_xor(s1p, off);
    }
    __shared__ float red0[2], red1[2];
    if ((t & 63) == 0) { red0[t >> 6] = s0p; red1[t >> 6] = s1p; }
    __syncthreads();
    if (t == 0) { sq0[bs] = red0[0] + red0[1]; sq1[bs] = red1[0] + red1[1]; }
}

// ---------- kernel 2: cross-GEMM (64x64 tile, K=512, chunk 128); writes A and A^T ----------
// T14 async-stage: next 128-k panels are loaded into VGPRs during the current
// MFMA phase, so the global->LDS latency hides under compute instead of being
// exposed between barriers.
__global__ __launch_bounds__(256) void gemm_cross_kernel(
    const u16* __restrict__ F0b, const u16* __restrict__ F1b,
    const float* __restrict__ sq0, const float* __restrict__ sq1,
    u16* __restrict__ Abf, u16* __restrict__ ATbf)
{
    __shared__ __align__(16) u16 smem[64 * 136 * 2];   // As | Bs, 34.8 KB -> 4 blk/CU
    u16 (*As)[136] = (u16(*)[136])smem;
    u16 (*Bs)[136] = (u16(*)[136])(smem + 64 * 136);

    int b = blockIdx.y;
    int i0 = (blockIdx.x >> 2) * 64, j0 = (blockIdx.x & 3) * 64;
    const u16* Ap = F0b + (size_t)b * 131072;
    const u16* Bp = F1b + (size_t)b * 131072;
    const float* sqR = sq0 + b * 256;
    const float* sqC = sq1 + b * 256;

    const int t = threadIdx.x;
    const int lane = t & 63, w = t >> 6;
    const int wm = w >> 1, wn = w & 1;
    const int q = lane >> 4, lm = lane & 15;

    f32x4 acc[2][2];
    #pragma unroll
    for (int x = 0; x < 2; ++x)
        #pragma unroll
        for (int y = 0; y < 2; ++y)
            acc[x][y] = (f32x4){0.f, 0.f, 0.f, 0.f};

    // prologue: load first 128-k panels into regs
    uint4 ar[4], br[4];
    #pragma unroll
    for (int i = 0; i < 4; ++i) {
        int idx = i * 256 + t, row = idx >> 4, seg = idx & 15;
        ar[i] = *(const uint4*)(Ap + (size_t)(i0 + row) * 512 + seg * 8);
        br[i] = *(const uint4*)(Bp + (size_t)(j0 + row) * 512 + seg * 8);
    }

    for (int k0 = 0; k0 < 512; k0 += 128) {
        if (k0) __syncthreads();          // previous MFMA readers done
        #pragma unroll
        for (int i = 0; i < 4; ++i) {
            int idx = i * 256 + t, row = idx >> 4, seg = idx & 15;
            *(uint4*)&As[row][seg * 8] = ar[i];
            *(uint4*)&Bs[row][seg * 8] = br[i];
        }
        if (k0 + 128 < 512) {             // prefetch next panels (consumed after next barrier)
            #pragma unroll
            for (int i = 0; i < 4; ++i) {
                int idx = i * 256 + t, row = idx >> 4, seg = idx & 15;
                ar[i] = *(const uint4*)(Ap + (size_t)(i0 + row) * 512 + (k0 + 128) + seg * 8);
                br[i] = *(const uint4*)(Bp + (size_t)(j0 + row) * 512 + (k0 + 128) + seg * 8);
            }
        }
        __syncthreads();
        #pragma unroll
        for (int ks = 0; ks < 128; ks += 32) {
            short8 af[2], bfr[2];
            #pragma unroll
            for (int x = 0; x < 2; ++x) {
                af[x]  = *(const short8*)&As[wm * 32 + x * 16 + lm][ks + q * 8];
                bfr[x] = *(const short8*)&Bs[wn * 32 + x * 16 + lm][ks + q * 8];
            }
            #pragma unroll
            for (int x = 0; x < 2; ++x)
                #pragma unroll
                for (int y = 0; y < 2; ++y)
                    acc[x][y] = __builtin_amdgcn_mfma_f32_16x16x32_bf16(
                        af[x], bfr[y], acc[x][y], 0, 0, 0);
        }
    }
    __syncthreads();

    // epilogue: A values into LDS tile (alias As), then vectorized A and A^T stores
    u16 (*Ct)[136] = (u16(*)[136])smem;
    #pragma unroll
    for (int x = 0; x < 2; ++x) {
        #pragma unroll
        for (int r = 0; r < 4; ++r) {
            int ir = wm * 32 + x * 16 + q * 4 + r;
            float si = sqR[i0 + ir];
            #pragma unroll
            for (int y = 0; y < 2; ++y) {
                int jc = wn * 32 + y * 16 + lm;
                float d2 = si + sqC[j0 + jc] - 2.f * acc[x][y][r];
                d2 = fmaxf(d2, 0.f);
                float a = 1.f / (1.f + sqrtf(d2));
                Ct[ir][jc] = f2bf(a);
            }
        }
    }
    __syncthreads();

    u16* Aout  = Abf  + (size_t)b * 65536;
    u16* ATout = ATbf + (size_t)b * 65536;
    int ii = t >> 2;              // 0..63
    int c0 = (t & 3) * 16;        // 0,16,32,48
    #pragma unroll
    for (int c = 0; c < 4; ++c) { // A: row-major, vectorized
        ushort4 v = *(ushort4*)&Ct[ii][c0 + c * 4];
        *(ushort4*)&Aout[(size_t)(i0 + ii) * 256 + j0 + c0 + c * 4] = v;
    }
    #pragma unroll
    for (int c = 0; c < 4; ++c) { // A^T: transpose-read from LDS
        ushort4 v;
        v.x = Ct[c0 + c * 4 + 0][ii];
        v.y = Ct[c0 + c * 4 + 1][ii];
        v.z = Ct[c0 + c * 4 + 2][ii];
        v.w = Ct[c0 + c * 4 + 3][ii];
        *(ushort4*)&ATout[(size_t)(j0 + ii) * 256 + i0 + c0 + c * 4] = v;
    }
}

// ---------- kernel 3: fused Fa-GEMM + conv + tanh + avgpool ----------
// Block: 32 out rows x 512 d, one (batch, side). Fa never hits HBM.
// LDS diet: Al shrunk to 36 rows (dead fragment rows clamped; their outputs are
// discarded by the m<36 guard), Fl aliased onto Bl (disjoint lifetimes).
// 53.7 KB -> 36.6 KB => 4 blocks/CU. WT staging + conv F reads are
// register-prefetched so global latency hides under the MFMA phase (T14).
__global__ __launch_bounds__(256, 4) void fa_conv_kernel(
    const u16* __restrict__ Abf, const u16* __restrict__ ATbf,
    const u16* __restrict__ WT0, const u16* __restrict__ WT1,
    const u16* __restrict__ F0b, const u16* __restrict__ F1b,
    const float* __restrict__ cw, const float* __restrict__ cb,
    float* __restrict__ out)
{
    __shared__ __align__(16) u16 Al[36][264];     // A rows (36 used) x K=256, 19.0 KB
    __shared__ __align__(16) u16 BlFl[128 * 72];  // Bl [128][72] 18.4 KB; Fl [36][132] aliased
    u16 (*Bl)[72]  = (u16(*)[72])BlFl;
    u16 (*Fl)[132] = (u16(*)[132])BlFl;

    int b = blockIdx.y, side = blockIdx.z;
    int s0 = blockIdx.x * 32;
    const u16* Ap = (side ? Abf : ATbf) + (size_t)b * 65536;
    const u16* WT = side ? WT1 : WT0;
    const u16* Fb = (side ? F1b : F0b) + (size_t)b * 131072;
    float* o = out + (size_t)side * 8388608 + (size_t)b * 131072;

    const int t = threadIdx.x;
    const int lane = t & 63, w = t >> 6;
    const int q = lane >> 4, lm = lane & 15;

    // stage A once: rows r=0..35 <-> s = s0-2+r; zero when s OOB
    #pragma unroll
    for (int i = 0; i < 5; ++i) {
        int idx = i * 256 + t;          // 0..1279, use 0..1151
        if (idx < 1152) {
            int r = idx >> 5;           // 0..35
            int seg = idx & 31;         // 32 segs of 8 bf16
            int s = s0 - 2 + r;
            uint4 v = {0u, 0u, 0u, 0u};
            if ((unsigned)s < 256u)
                v = *(const uint4*)(Ap + (size_t)s * 256 + seg * 8);
            *(uint4*)&Al[r][seg * 8] = v;
        }
    }

    // A-fragment row pointers; x=2 rows >=36 are dead (outputs discarded) -> clamp to row 0
    const u16* aRow[3];
    aRow[0] = &Al[lm][0];
    aRow[1] = &Al[16 + lm][0];
    aRow[2] = &Al[(lm < 4) ? (32 + lm) : 0][0];

    float w00 = cw[0], w01 = cw[1], w02 = cw[2];
    float w10 = cw[3], w11 = cw[4], w12 = cw[5];
    float bias = cb[0];
    const float third = 1.f / 3.f;
    const int g = t >> 5;               // 0..7: out-row group (4 rows)
    const int dl = (t & 31) * 4;        // d within chunk

    // prologue: first WT chunk (n0=0, kb=0) into regs
    uint4 brg[4];
    #pragma unroll
    for (int i = 0; i < 4; ++i) {
        int idx = i * 256 + t, r = idx >> 3, seg = idx & 7;
        brg[i] = *(const uint4*)(WT + (size_t)r * 256 + seg * 8);
    }

    for (int n0 = 0; n0 < 512; n0 += 128) {
        // prefetch conv F reads for this d-chunk: hides under the whole GEMM phase
        ushort4 frg[8];
        #pragma unroll
        for (int k = 0; k < 8; ++k) {
            int s = s0 + g * 4 - 2 + k;
            ushort4 z = {0, 0, 0, 0};
            frg[k] = ((unsigned)s < 256u)
                   ? *(const ushort4*)(Fb + (size_t)s * 512 + n0 + dl) : z;
        }

        f32x4 acc[3][2];
        #pragma unroll
        for (int x = 0; x < 3; ++x)
            #pragma unroll
            for (int y = 0; y < 2; ++y)
                acc[x][y] = (f32x4){0.f, 0.f, 0.f, 0.f};

        for (int kb = 0; kb < 256; kb += 64) {
            __syncthreads();            // prior Bl/Fl readers done
            #pragma unroll
            for (int i = 0; i < 4; ++i) {
                int idx = i * 256 + t, r = idx >> 3, seg = idx & 7;
                *(uint4*)&Bl[r][seg * 8] = brg[i];
            }
            if (kb < 192) {             // prefetch next k-chunk during MFMA phase
                #pragma unroll
                for (int i = 0; i < 4; ++i) {
                    int idx = i * 256 + t, r = idx >> 3, seg = idx & 7;
                    brg[i] = *(const uint4*)(WT + (size_t)(n0 + r) * 256 + (kb + 64) + seg * 8);
                }
            }
            __syncthreads();
            #pragma unroll
            for (int ks = 0; ks < 64; ks += 32) {
                short8 af[3], bfr[2];
                #pragma unroll
                for (int x = 0; x < 3; ++x)
                    af[x] = *(const short8*)(aRow[x] + kb + ks + q * 8);
                #pragma unroll
                for (int y = 0; y < 2; ++y)
                    bfr[y] = *(const short8*)&Bl[w * 32 + y * 16 + lm][ks + q * 8];
                #pragma unroll
                for (int x = 0; x < 3; ++x)
                    #pragma unroll
                    for (int y = 0; y < 2; ++y)
                        acc[x][y] = __builtin_amdgcn_mfma_f32_16x16x32_bf16(
                            af[x], bfr[y], acc[x][y], 0, 0, 0);
            }
        }
        __syncthreads();                // Bl dead from here: Fl takes over the space

        // stage Fa (bf16) into LDS (aliases Bl)
        #pragma unroll
        for (int x = 0; x < 3; ++x)
            #pragma unroll
            for (int r = 0; r < 4; ++r) {
                int m = x * 16 + q * 4 + r;
                if (m < 36) {
                    #pragma unroll
                    for (int y = 0; y < 2; ++y)
                        Fl[m][w * 32 + y * 16 + lm] = f2bf(acc[x][y][r]);
                }
            }
        if (n0 < 384) {                 // prefetch next n0's first WT chunk during conv phase
            #pragma unroll
            for (int i = 0; i < 4; ++i) {
                int idx = i * 256 + t, r = idx >> 3, seg = idx & 7;
                brg[i] = *(const uint4*)(WT + (size_t)(n0 + 128 + r) * 256 + seg * 8);
            }
        }
        __syncthreads();

        // conv + tanh + avgpool for this 128-d chunk; thread: 4 out rows x 4 d
        float4 f[8], a[8];
        #pragma unroll
        for (int k = 0; k < 8; ++k) {
            f[k] = bf4f(frg[k]);
            a[k] = bf4f(*(const ushort4*)&Fl[g * 4 + k][dl]);
        }
        float4 ty[6];
        #pragma unroll
        for (int k = 0; k < 6; ++k) {
            float4 y;
            y.x = bias + w00*f[k].x + w01*f[k+1].x + w02*f[k+2].x + w10*a[k].x + w11*a[k+1].x + w12*a[k+2].x;
            y.y = bias + w00*f[k].y + w01*f[k+1].y + w02*f[k+2].y + w10*a[k].y + w11*a[k+1].y + w12*a[k+2].y;
            y.z = bias + w00*f[k].z + w01*f[k+1].z + w02*f[k+2].z + w10*a[k].z + w11*a[k+1].z + w12*a[k+2].z;
            y.w = bias + w00*f[k].w + w01*f[k+1].w + w02*f[k+2].w + w10*a[k].w + w11*a[k+1].w + w12*a[k+2].w;
            y.x = ftanh(y.x); y.y = ftanh(y.y); y.z = ftanh(y.z); y.w = ftanh(y.w);
            ty[k] = y;
        }
        #pragma unroll
        for (int r = 0; r < 4; ++r) {
            float4 res;
            res.x = (ty[r].x + ty[r+1].x + ty[r+2].x) * third;
            res.y = (ty[r].y + ty[r+1].y + ty[r+2].y) * third;
            res.z = (ty[r].z + ty[r+1].z + ty[r+2].z) * third;
            res.w = (ty[r].w + ty[r+1].w + ty[r+2].w) * third;
            *(float4*)(o + (size_t)(s0 + g * 4 + r) * 512 + n0 + dl) = res;
        }
        // next iteration's top-of-kb-loop barrier protects Fl before Bl overwrite
    }
}

// ---------- launcher ----------
extern "C" void kernel_launch(void* const* d_in, const int* in_sizes, int n_in,
                              void* d_out, int out_size, void* d_ws, size_t ws_size,
                              hipStream_t stream)
{
    const float* F0r = (const float*)d_in[0];
    const float* F1r = (const float*)d_in[1];
    const float* m0  = (const float*)d_in[2];
    const float* m1  = (const float*)d_in[3];
    const float* W0  = (const float*)d_in[4];
    const float* W1  = (const float*)d_in[5];
    const float* cw  = (const float*)d_in[6];
    const float* cb  = (const float*)d_in[7];
    float* out = (float*)d_out;

    char* ws = (char*)d_ws;
    u16* F0b   = (u16*)(ws);                      // 16 MiB  [B,S,D] bf16
    u16* F1b   = (u16*)(ws + 16777216);           // 16 MiB
    u16* Abf   = (u16*)(ws + 33554432);           // 8 MiB   [B,S,S] bf16
    u16* ATbf  = (u16*)(ws + 41943040);           // 8 MiB
    float* sq0 = (float*)(ws + 50331648);         // 64 KiB
    float* sq1 = (float*)(ws + 50397184);         // 64 KiB
    u16* WT0   = (u16*)(ws + 50462720);           // 256 KiB [D,S] bf16
    u16* WT1   = (u16*)(ws + 50724864);           // 256 KiB

    prep_kernel<<<18432, 128, 0, stream>>>(F0r, F1r, m0, m1, W0, W1,
                                           F0b, F1b, WT0, WT1, sq0, sq1);
    gemm_cross_kernel<<<dim3(16, 64), 256, 0, stream>>>(F0b, F1b, sq0, sq1, Abf, ATbf);
    fa_conv_kernel<<<dim3(8, 64, 2), 256, 0, stream>>>(Abf, ATbf, WT0, WT1,
                                                       F0b, F1b, cw, cb, out);
}